// Round 15
// baseline (755.653 us; speedup 1.0000x reference)
//
#include <hip/hip_runtime.h>
#include <hip/hip_bf16.h>
#include <stdint.h>

typedef unsigned short u16;
typedef unsigned int   u32;
typedef float f32x4  __attribute__((ext_vector_type(4)));
typedef short bf16x8 __attribute__((ext_vector_type(8)));

#define NSEQ 800
#define TOUT 12
#define NC   9
#define LOG2E  1.44269504088896340736f
#define LOG2E2 2.88539008177792681472f

// ---- Round-32: R31 minus x-prefetch -> 16 fewer arch VGPRs -> 2 blocks/CU ----
// R31 (724 us hot): VALU busy 463 us; remaining ~260 us = serial-chain stall at
// 1 block/CU. Unified RF: 4 waves/SIMD (2 blocks) iff arch+AGPR <= 128/wave.
// R31 was 112 arch + ~16 acc AGPR = boundary; granularity rounding -> 3 w/SIMD.
// R32 drops the encoder x-prefetch (16 live regs; worth only ~40us in R26):
// arch ~96 + 16 AGPR = 112 -> 4 waves/SIMD -> 2 blocks/CU (~39% occ).
// LDS 2x77824 = 155648 <= 163840 fits (enabled by R31's BXD removal).
// If occupancy stays ~20%: AGPR accounting is a hard lock -> structure ceiling.
#define WIMG_STRIDE 73728
#define LDS_BHE 0
#define LDS_BXE 24576
#define LDS_BHD 36864
#define LDS_H   61440
#define LDS_TOTAL 77824
#define BIASE_OFF 663552
#define BIASD_OFF 672768
#define WGT_OFF   681984

__device__ __forceinline__ u16 f2bf(float f){ union{float f;u32 i;}v; v.f=f; u32 x=v.i; return (u16)((x + 0x7fffu + ((x>>16)&1u))>>16); }
__device__ __forceinline__ u32 pkbf(float a, float b){
  union{ __hip_bfloat162 h2; u32 u; } v;
  v.h2 = __float22bfloat162_rn(float2{a,b});
  return v.u;
}

union BXU { uint4 u; bf16x8 v; };

// ================= prep kernel: build LDS images + biases + softmax ==========
__global__ void prep_kernel(
  const float* __restrict__ cw2, const float* __restrict__ cw3, const float* __restrict__ cw4,
  const float* __restrict__ cbv,
  const float* __restrict__ Ewih, const float* __restrict__ Ewhh,
  const float* __restrict__ Ebih, const float* __restrict__ Ebhh,
  const float* __restrict__ Dwih, const float* __restrict__ Dwhh,
  const float* __restrict__ Dbih, const float* __restrict__ Dbhh,
  const float* __restrict__ emb,
  char* __restrict__ ws)
{
  const int r = blockIdx.x;
  const int tid = threadIdx.x;
  const int K = (r<3) ? 2 : ((r<6) ? 3 : 4);
  char* wimg = ws + (size_t)r*WIMG_STRIDE;

  const float* ewhh = Ewhh + (size_t)r*192*64;
  const float* dwhh = Dwhh + (size_t)r*192*64;
  #pragma unroll 1
  for (int s = tid; s < 1536; s += 512){
    int g = s >> 6, fl = s & 63;
    int ks = g/12, nt = g%12;
    int col = nt*16 + (fl&15);
    float sc = (nt<8) ? LOG2E : LOG2E2;
    u32 we[4] = {0,0,0,0}, wd[4] = {0,0,0,0};
    #pragma unroll
    for (int j=0;j<8;j++){
      int hid = ((j&3)<<4) | (ks*8 + (fl>>4)*2 + (j>>2));
      we[j>>1] |= (u32)f2bf(sc * ewhh[col*64 + hid]) << ((j&1)*16);
      wd[j>>1] |= (u32)f2bf(sc * dwhh[col*64 + hid]) << ((j&1)*16);
    }
    *(uint4*)(wimg + LDS_BHE + s*16) = uint4{we[0],we[1],we[2],we[3]};
    *(uint4*)(wimg + LDS_BHD + s*16) = uint4{wd[0],wd[1],wd[2],wd[3]};
  }
  const float* wih = Ewih + r*192*8;
  const float* cw  = (r<3) ? (cw2 + r*128) : (r<6) ? (cw3 + (r-3)*192) : (cw4 + (r-6)*256);
  #pragma unroll 1
  for (int s = tid; s < 768; s += 512){
    int g = s >> 6, fl = s & 63;
    int col = g*16 + (fl&15);
    int tap = fl>>4;
    float sc = (g<8) ? LOG2E : LOG2E2;
    u32 w[4] = {0,0,0,0};
    if (tap < K){
      #pragma unroll
      for (int j=0;j<8;j++){
        float a = 0.f;
        #pragma unroll
        for (int o=0;o<8;o++) a += wih[col*8+o]*cw[(o*8+j)*K + tap];
        w[j>>1] |= (u32)f2bf(sc*a) << ((j&1)*16);
      }
    }
    *(uint4*)(wimg + LDS_BXE + s*16) = uint4{w[0],w[1],w[2],w[3]};
  }
  if (tid < 16){
    int n = tid;
    const float* bi = Ebih + r*192; const float* bh2 = Ebhh + r*192;
    const float* cb = cbv + r*8;
    float* be = (float*)(ws + BIASE_OFF) + ((size_t)r*16 + n)*16;
    #pragma unroll
    for (int ht=0; ht<4; ht++){
      int hid = ht*16 + n;
      float cR=0.f,cZ=0.f,cN=0.f;
      #pragma unroll
      for (int o=0;o<8;o++){
        cR += wih[hid*8+o]*cb[o];
        cZ += wih[(64+hid)*8+o]*cb[o];
        cN += wih[(128+hid)*8+o]*cb[o];
      }
      be[ht]    = LOG2E  * (bi[hid]     + bh2[hid]     + cR);
      be[4+ht]  = LOG2E  * (bi[64+hid]  + bh2[64+hid]  + cZ);
      be[8+ht]  = LOG2E2 * (bi[128+hid]                + cN);
      be[12+ht] = LOG2E2 *                bh2[128+hid];
    }
  } else if (tid < 32){
    int n = tid - 16;
    const float* bi = Dbih + r*192; const float* bh2 = Dbhh + r*192;
    float* bd = (float*)(ws + BIASD_OFF) + ((size_t)r*16 + n)*16;
    #pragma unroll
    for (int ht=0; ht<4; ht++){
      int hid = ht*16 + n;
      bd[ht]    = LOG2E  * (bi[hid]     + bh2[hid]);
      bd[4+ht]  = LOG2E  * (bi[64+hid]  + bh2[64+hid]);
      bd[8+ht]  = LOG2E2 *  bi[128+hid];
      bd[12+ht] = LOG2E2 *  bh2[128+hid];
    }
  }
  if (r == 0){
    float* wg = (float*)(ws + WGT_OFF);
    #pragma unroll 1
    for (int nb = tid; nb < NSEQ; nb += 512){
      float e[NC], mx = -1e30f;
      #pragma unroll
      for (int c=0;c<NC;c++){ e[c] = emb[nb*NC+c]; mx = fmaxf(mx, e[c]); }
      float sm = 0.f;
      #pragma unroll
      for (int c=0;c<NC;c++){ e[c] = __expf(e[c]-mx); sm += e[c]; }
      float inv = 1.f/sm;
      #pragma unroll
      for (int c=0;c<NC;c++) wg[nb*NC+c] = e[c]*inv;
    }
  }
}

// ================= main kernel ==============================================
__global__ __launch_bounds__(512, 2) void rnn_kernel(
  const float* __restrict__ X,
  const float* __restrict__ Dwih,
  const float* __restrict__ Lw, const float* __restrict__ Lb,
  const char* __restrict__ ws,
  float* __restrict__ out)
{
  __shared__ char LDSC[LDS_TOTAL];
  const int tid = threadIdx.x;
  const int wv  = tid >> 6;
  const int l   = tid & 63;
  const int q   = l >> 4;
  const int n   = l & 15;
  const int r   = blockIdx.y;
  const int seqb = blockIdx.x*128 + wv*16;

  const int Kc[NC]={2,2,2,3,3,3,4,4,4};
  const int Dc[NC]={1,2,4,1,2,4,1,2,4};
  const int K = Kc[r], D = Dc[r];
  const int L = 15 - (K-1)*D;

  // zero own h slice (wave-private)
  const int HB = LDS_H + wv*2048;
  *(uint4*)(LDSC + HB + l*32)      = uint4{0,0,0,0};
  *(uint4*)(LDSC + HB + l*32 + 16) = uint4{0,0,0,0};

  // coalesced copy of BHE+BXE+BHD (3840 uint4)
  {
    const uint4* src = (const uint4*)(ws + (size_t)r*WIMG_STRIDE);
    #pragma unroll 1
    for (int it=0; it<8; it++){
      int idx = it*512 + tid;
      if (idx < 3840) *(uint4*)(LDSC + idx*16) = src[idx];
    }
  }

  // encoder biases from ws
  float bR4[4], bZ4[4], bNi4[4], bNh4[4];
  {
    const float* be = (const float*)(ws + BIASE_OFF) + ((size_t)r*16 + n)*16;
    float4 v0 = *(const float4*)(be);
    float4 v1 = *(const float4*)(be+4);
    float4 v2 = *(const float4*)(be+8);
    float4 v3 = *(const float4*)(be+12);
    bR4[0]=v0.x; bR4[1]=v0.y; bR4[2]=v0.z; bR4[3]=v0.w;
    bZ4[0]=v1.x; bZ4[1]=v1.y; bZ4[2]=v1.z; bZ4[3]=v1.w;
    bNi4[0]=v2.x; bNi4[1]=v2.y; bNi4[2]=v2.z; bNi4[3]=v2.w;
    bNh4[0]=v3.x; bNh4[1]=v3.y; bNh4[2]=v3.z; bNh4[3]=v3.w;
  }

  float hO[4][4];
  #pragma unroll
  for (int ht=0;ht<4;ht++) for (int i=0;i<4;i++) hO[ht][i]=0.f;

  const int ra0 = HB + n*128 + (((  q + n)&7)<<4);
  const int ra1 = HB + n*128 + (((4+q + n)&7)<<4);
  int wa[4];
  #pragma unroll
  for (int i=0;i<4;i++){
    int seq = q*4+i;
    wa[i] = HB + seq*128 + ((((n>>1) + seq)&7)<<4) + ((n&1)<<3);
  }

  // fused pointwise: hn = [En(Ez+h)+(h-Ez)] / [(En+1)(Ez+1)]
#define POINTWISE(aR_,aZ_,aNi_,aNh_,HT) \
    _Pragma("unroll") \
    for (int i=0;i<4;i++){ \
      float Er = __builtin_amdgcn_exp2f(-aR_[i]); \
      float rr = __builtin_amdgcn_rcpf(1.f + Er); \
      float y  = aNi_[i] + rr*aNh_[i]; \
      float En = __builtin_amdgcn_exp2f(y); \
      float Ez = __builtin_amdgcn_exp2f(-aZ_[i]); \
      float h  = hO[HT][i]; \
      float e1 = En + 1.f; \
      float den = e1 + e1*Ez; \
      float num = En*(Ez+h) + (h-Ez); \
      float hn = num * __builtin_amdgcn_rcpf(den); \
      hO[HT][i] = hn; \
      if (HT==0)      hsv[i] = hn; \
      else if (HT==1) pk01[i] = pkbf(hsv[i], hn); \
      else if (HT==2) hsv[i] = hn; \
      else            pk23[i] = pkbf(hsv[i], hn); \
    }

  // ---- encoder GRU step ----
  auto step_core = [&](bf16x8 ax){
    bf16x8 a0 = *(const bf16x8*)(LDSC + ra0);
    bf16x8 a1 = *(const bf16x8*)(LDSC + ra1);
    float hsv[4]; u32 pk01[4], pk23[4];
    #pragma unroll
    for (int ht=0; ht<4; ht++){
      bf16x8 bR0 = *(const bf16x8*)(LDSC + LDS_BHE + ((      ht)*64 + l)*16);
      bf16x8 bR1 = *(const bf16x8*)(LDSC + LDS_BHE + ((12  + ht)*64 + l)*16);
      bf16x8 bZ0 = *(const bf16x8*)(LDSC + LDS_BHE + (( 4 + ht)*64 + l)*16);
      bf16x8 bZ1 = *(const bf16x8*)(LDSC + LDS_BHE + ((16  + ht)*64 + l)*16);
      bf16x8 bN0 = *(const bf16x8*)(LDSC + LDS_BHE + (( 8 + ht)*64 + l)*16);
      bf16x8 bN1 = *(const bf16x8*)(LDSC + LDS_BHE + ((20  + ht)*64 + l)*16);
      bf16x8 xR  = *(const bf16x8*)(LDSC + LDS_BXE + ((      ht)*64 + l)*16);
      bf16x8 xZ  = *(const bf16x8*)(LDSC + LDS_BXE + (( 4 + ht)*64 + l)*16);
      bf16x8 xN  = *(const bf16x8*)(LDSC + LDS_BXE + (( 8 + ht)*64 + l)*16);
      f32x4 aR  = f32x4{bR4[ht],bR4[ht],bR4[ht],bR4[ht]};
      f32x4 aZ  = f32x4{bZ4[ht],bZ4[ht],bZ4[ht],bZ4[ht]};
      f32x4 aNi = f32x4{bNi4[ht],bNi4[ht],bNi4[ht],bNi4[ht]};
      f32x4 aNh = f32x4{bNh4[ht],bNh4[ht],bNh4[ht],bNh4[ht]};
      aR = __builtin_amdgcn_mfma_f32_16x16x32_bf16(a0, bR0, aR,0,0,0);
      aR = __builtin_amdgcn_mfma_f32_16x16x32_bf16(a1, bR1, aR,0,0,0);
      aR = __builtin_amdgcn_mfma_f32_16x16x32_bf16(ax, xR,  aR,0,0,0);
      aZ = __builtin_amdgcn_mfma_f32_16x16x32_bf16(a0, bZ0, aZ,0,0,0);
      aZ = __builtin_amdgcn_mfma_f32_16x16x32_bf16(a1, bZ1, aZ,0,0,0);
      aZ = __builtin_amdgcn_mfma_f32_16x16x32_bf16(ax, xZ,  aZ,0,0,0);
      aNh= __builtin_amdgcn_mfma_f32_16x16x32_bf16(a0, bN0, aNh,0,0,0);
      aNh= __builtin_amdgcn_mfma_f32_16x16x32_bf16(a1, bN1, aNh,0,0,0);
      aNi= __builtin_amdgcn_mfma_f32_16x16x32_bf16(ax, xN,  aNi,0,0,0);
      POINTWISE(aR,aZ,aNi,aNh,ht)
    }
    #pragma unroll
    for (int i=0;i<4;i++){
      uint2 wv2; wv2.x = pk01[i]; wv2.y = pk23[i];
      *(uint2*)(LDSC + wa[i]) = wv2;
    }
  };

  // ---------- encoder: direct x load (no prefetch; TLP covers at 2 blocks) ----
  const float* xb = X + (size_t)(seqb + n)*120 + ((q<K)? q:0)*D*8;
  __syncthreads();   // the ONLY barrier
  #pragma unroll 1
  for (int t=0; t<L; t++){
    float4 v0 = *(const float4*)(xb + t*8);
    float4 v1 = *(const float4*)(xb + t*8 + 4);
    BXU a;
    a.u.x = __builtin_amdgcn_perm(__float_as_uint(v0.y), __float_as_uint(v0.x), 0x07060302u);
    a.u.y = __builtin_amdgcn_perm(__float_as_uint(v0.w), __float_as_uint(v0.z), 0x07060302u);
    a.u.z = __builtin_amdgcn_perm(__float_as_uint(v1.y), __float_as_uint(v1.x), 0x07060302u);
    a.u.w = __builtin_amdgcn_perm(__float_as_uint(v1.w), __float_as_uint(v1.z), 0x07060302u);
    step_core(a.v);
  }

  // ---------- decoder switch: NO barriers (BHD pre-staged) ----------
  {
    const float* bd = (const float*)(ws + BIASD_OFF) + ((size_t)r*16 + n)*16;
    float4 v0 = *(const float4*)(bd);
    float4 v1 = *(const float4*)(bd+4);
    float4 v2 = *(const float4*)(bd+8);
    float4 v3 = *(const float4*)(bd+12);
    bR4[0]=v0.x; bR4[1]=v0.y; bR4[2]=v0.z; bR4[3]=v0.w;
    bZ4[0]=v1.x; bZ4[1]=v1.y; bZ4[2]=v1.z; bZ4[3]=v1.w;
    bNi4[0]=v2.x; bNi4[1]=v2.y; bNi4[2]=v2.z; bNi4[3]=v2.w;
    bNh4[0]=v3.x; bNh4[1]=v3.y; bNh4[2]=v3.z; bNh4[3]=v3.w;
  }
  float dwR[4], dwZ[4], dwN[4];
  {
    const float* dwih = Dwih + r*192;
    #pragma unroll
    for (int ht=0; ht<4; ht++){
      int hid = ht*16 + n;
      dwR[ht] = LOG2E  * dwih[hid];
      dwZ[ht] = LOG2E  * dwih[64+hid];
      dwN[ht] = LOG2E2 * dwih[128+hid];
    }
  }
  float lwr[4];
  #pragma unroll
  for (int ht=0; ht<4; ht++) lwr[ht] = Lw[r*64 + ht*16 + n];
  const float lb_ = Lb[r];
  const float wgt = ((const float*)(ws + WGT_OFF))[((seqb + q*4 + (n&3)) % NSEQ)*NC + r];
  f32x4 lvv;
  #pragma unroll
  for (int i=0;i<4;i++) lvv[i] = X[(size_t)(seqb + q*4 + i)*120 + 112];

  // ---------- decoder: scalar-x steps, NO barriers, no broadcast ----------
  #pragma unroll 1
  for (int t=0; t<TOUT; t++){
    {
      bf16x8 a0 = *(const bf16x8*)(LDSC + ra0);
      bf16x8 a1 = *(const bf16x8*)(LDSC + ra1);
      float hsv[4]; u32 pk01[4], pk23[4];
      #pragma unroll
      for (int ht=0; ht<4; ht++){
        bf16x8 bR0 = *(const bf16x8*)(LDSC + LDS_BHD + ((      ht)*64 + l)*16);
        bf16x8 bR1 = *(const bf16x8*)(LDSC + LDS_BHD + ((12  + ht)*64 + l)*16);
        bf16x8 bZ0 = *(const bf16x8*)(LDSC + LDS_BHD + (( 4 + ht)*64 + l)*16);
        bf16x8 bZ1 = *(const bf16x8*)(LDSC + LDS_BHD + ((16  + ht)*64 + l)*16);
        bf16x8 bN0 = *(const bf16x8*)(LDSC + LDS_BHD + (( 8 + ht)*64 + l)*16);
        bf16x8 bN1 = *(const bf16x8*)(LDSC + LDS_BHD + ((20  + ht)*64 + l)*16);
        f32x4 aR, aZ, aNi, aNh;
        #pragma unroll
        for (int i=0;i<4;i++){
          aR[i]  = bR4[ht]  + lvv[i]*dwR[ht];
          aZ[i]  = bZ4[ht]  + lvv[i]*dwZ[ht];
          aNi[i] = bNi4[ht] + lvv[i]*dwN[ht];
          aNh[i] = bNh4[ht];
        }
        aR = __builtin_amdgcn_mfma_f32_16x16x32_bf16(a0, bR0, aR,0,0,0);
        aR = __builtin_amdgcn_mfma_f32_16x16x32_bf16(a1, bR1, aR,0,0,0);
        aZ = __builtin_amdgcn_mfma_f32_16x16x32_bf16(a0, bZ0, aZ,0,0,0);
        aZ = __builtin_amdgcn_mfma_f32_16x16x32_bf16(a1, bZ1, aZ,0,0,0);
        aNh= __builtin_amdgcn_mfma_f32_16x16x32_bf16(a0, bN0, aNh,0,0,0);
        aNh= __builtin_amdgcn_mfma_f32_16x16x32_bf16(a1, bN1, aNh,0,0,0);
        POINTWISE(aR,aZ,aNi,aNh,ht)
      }
      #pragma unroll
      for (int i=0;i<4;i++){
        uint2 wv2; wv2.x = pk01[i]; wv2.y = pk23[i];
        *(uint2*)(LDSC + wa[i]) = wv2;
      }
    }
    float p[4];
    #pragma unroll
    for (int i=0;i<4;i++)
      p[i] = hO[0][i]*lwr[0] + hO[1][i]*lwr[1] + hO[2][i]*lwr[2] + hO[3][i]*lwr[3];
    #pragma unroll
    for (int m=1; m<16; m<<=1){
      #pragma unroll
      for (int i=0;i<4;i++) p[i] += __shfl_xor(p[i], m, 64);
    }
    #pragma unroll
    for (int i=0;i<4;i++) lvv[i] = p[i] + lb_;
    if (n < 4){
      float vout = (n&2) ? ((n&1)? lvv[3] : lvv[2]) : ((n&1)? lvv[1] : lvv[0]);
      atomicAdd(out + (size_t)(seqb + q*4 + n)*TOUT + t, wgt*vout);
    }
  }
}

extern "C" void kernel_launch(void* const* d_in, const int* in_sizes, int n_in,
                              void* d_out, int out_size, void* d_ws, size_t ws_size,
                              hipStream_t stream)
{
  float* out = (float*)d_out;
  hipMemsetAsync(out, 0, (size_t)out_size*sizeof(float), stream);

  prep_kernel<<<dim3(NC), 512, 0, stream>>>(
    (const float*)d_in[2], (const float*)d_in[3], (const float*)d_in[4],
    (const float*)d_in[5],
    (const float*)d_in[6], (const float*)d_in[7], (const float*)d_in[8], (const float*)d_in[9],
    (const float*)d_in[10],(const float*)d_in[11],(const float*)d_in[12],(const float*)d_in[13],
    (const float*)d_in[16],
    (char*)d_ws);

  dim3 g(NSEQ*64/128, NC);
  rnn_kernel<<<g, 512, 0, stream>>>(
    (const float*)d_in[1],
    (const float*)d_in[10],
    (const float*)d_in[14], (const float*)d_in[15],
    (const char*)d_ws,
    out);
}